// Round 9
// baseline (587.014 us; speedup 1.0000x reference)
//
#include <hip/hip_runtime.h>
#include <hip/hip_bf16.h>
#include <math.h>

#define Bv 64
#define Jv 20000
#define NJT 625   // j tiles (32 j each)
#define NBT 8     // b tiles (8 b each)
#define NBLK (NBT * NJT)

typedef __attribute__((ext_vector_type(8))) short short8;
typedef __attribute__((ext_vector_type(4))) float f32x4;

union U8 { short8 s; unsigned int u[4]; };

__device__ __forceinline__ unsigned short f2bf(float f) {
  unsigned int u = __float_as_uint(f);
  u += 0x7FFFu + ((u >> 16) & 1u);
  return (unsigned short)(u >> 16);
}
__device__ __forceinline__ unsigned int pkbf(float a, float b) {
  __hip_bfloat162 h = __float22bfloat162_rn(make_float2(a, b));
  union { __hip_bfloat162 h; unsigned int u; } c;
  c.h = h;
  return c.u;  // a in low 16, b in high 16
}
__device__ __forceinline__ float bflo(unsigned int u) { return __uint_as_float(u << 16); }
__device__ __forceinline__ float bfhi(unsigned int u) { return __uint_as_float(u & 0xFFFF0000u); }

// Block = 32 j x 8 b = 256 pairs (m = j*8 + b), 256 threads.
// pre1 / h@W2 / gate-L1 / e-h reduce all via MFMA. Tail (c-layer + encoder
// MLP) fused: last block to finish (device-scope counter) runs it, reading
// acc/se via device-scope atomic loads.
__global__ __launch_bounds__(256) void pe_fused(
    const float* __restrict__ x, const int* __restrict__ mask,
    const int* __restrict__ atse_idx, const float* __restrict__ fe,
    const float* __restrict__ ae,
    const float* __restrict__ hW1, const float* __restrict__ hb1,
    const float* __restrict__ hl1g, const float* __restrict__ hl1b,
    const float* __restrict__ hW2, const float* __restrict__ hb2,
    const float* __restrict__ hl2g, const float* __restrict__ hl2b,
    const float* __restrict__ gW1, const float* __restrict__ gb1,
    const float* __restrict__ gW2, const float* __restrict__ gb2,
    const float* __restrict__ cW, const float* __restrict__ cb,
    const float* __restrict__ clng, const float* __restrict__ clnb,
    const float* __restrict__ eW1, const float* __restrict__ eb1,
    const float* __restrict__ eW2, const float* __restrict__ eb2,
    float* __restrict__ acc_g, float* __restrict__ se_g,
    int* __restrict__ cnt, float* __restrict__ out) {
  __shared__ __align__(16) float s_pg[32 * 68];      // pre1, then pre1*gamma
  __shared__ __align__(16) float s_ex[32 * 4];       // sp, qp, dwp per j
  __shared__ __align__(16) float s_gb[32 * 28 + 16]; // gate bias per j (+pad)
  __shared__ __align__(16) float s_pair[256 * 4];    // P3-P4: pair scalars; P5-P6: e
  __shared__ __align__(16) float s_w0[64], s_w0g[64], s_l1g[64], s_l1b[64];
  __shared__ __align__(16) float s_b2[32], s_l2g[32], s_l2b[32];
  __shared__ __align__(16) float s_gb1[24], s_gW2[96];
  __shared__ float s_gb2[4], s_scal[2];
  __shared__ int s_mk[256];
  __shared__ int s_last;
  __shared__ __align__(16) unsigned short s_gW1bf[32 * 24];
  // overlay: P0-P3 (float): [0..2048) W2 | [2048..2688) ae | [2688..3072) gW1b
  //          P4-P6: s_h bf16 [256][34];  tail: 4 x 288-float wave scratch
  __shared__ __align__(16) unsigned short s_ovl[256 * 34];

  int tid = threadIdx.x;
  int btile = blockIdx.x;   // 0..7
  int jtile = blockIdx.y;   // 0..624
  int J0 = jtile * 32;
  int lane = tid & 63, wv = tid >> 6;
  int li = lane & 15, quad = lane >> 4;

  float* ovlf = (float*)s_ovl;
  float* s_aeo = ovlf + 2048;
  float* s_gW1bo = ovlf + 2688;
  unsigned short* s_h = s_ovl;  // ho bf16, stride 34 (P4+)

  // ---------------- P0: stage globals ----------------
  for (int i = tid; i < 2048; i += 256) ovlf[i] = hW2[i];
  for (int i = tid; i < 768; i += 256) s_gW1bf[i] = f2bf(gW1[i]);
  for (int i = tid; i < 384; i += 256) s_gW1bo[i] = gW1[768 + i];
  if (tid < 96) s_gW2[tid] = gW2[tid];
  if (tid < 64) { s_w0[tid] = hW1[tid]; s_l1g[tid] = hl1g[tid]; s_l1b[tid] = hl1b[tid]; }
  if (tid < 32) { s_b2[tid] = hb2[tid]; s_l2g[tid] = hl2g[tid]; s_l2b[tid] = hl2b[tid]; }
  if (tid < 24) s_gb1[tid] = gb1[tid];
  if (tid < 4) s_gb2[tid] = gb2[tid];
  if (tid < 128) s_gb[(tid >> 2) * 28 + 24 + (tid & 3)] = 0.f;  // cols 24..27
  if (tid >= 128 && tid < 144) s_gb[32 * 28 + (tid - 128)] = 0.f;
  if (tid < 32) {
    int ai = atse_idx[J0 + tid];
    const float4* av = (const float4*)(ae + (size_t)ai * 16);
#pragma unroll
    for (int q = 0; q < 4; ++q) *(float4*)(s_aeo + tid * 20 + q * 4) = av[q];
  }
  __syncthreads();

  // ---------------- P1: pre1 via MFMA ----------------
  {
    U8 bH;
#pragma unroll
    for (int p = 0; p < 4; ++p) {
      float lo = hW1[(1 + quad * 8 + 2 * p) * 64 + wv * 16 + li];
      float hi = hW1[(1 + quad * 8 + 2 * p + 1) * 64 + wv * 16 + li];
      bH.u[p] = pkbf(lo, hi);
    }
    float hb = hb1[wv * 16 + li];
    f32x4 cP;
#pragma unroll
    for (int mt = 0; mt < 2; ++mt) {
      cP[0] = hb; cP[1] = hb; cP[2] = hb; cP[3] = hb;
      const float* fp = fe + (size_t)(J0 + mt * 16 + li) * 32 + quad * 8;
      float4 f0 = *(const float4*)fp;
      float4 f1 = *(const float4*)(fp + 4);
      U8 aF;
      aF.u[0] = pkbf(f0.x, f0.y); aF.u[1] = pkbf(f0.z, f0.w);
      aF.u[2] = pkbf(f1.x, f1.y); aF.u[3] = pkbf(f1.z, f1.w);
      cP = __builtin_amdgcn_mfma_f32_16x16x32_bf16(aF.s, bH.s, cP, 0, 0, 0);
#pragma unroll
      for (int r = 0; r < 4; ++r)
        s_pg[(mt * 16 + quad * 4 + r) * 68 + wv * 16 + li] = cP[r];
    }
  }
  // gate bias per j (8 threads per j, 3 c's per thread)
  {
    int jp = tid >> 3, ks = tid & 7;
    int c0 = ks * 3;
    float g3[3] = {s_gb1[c0], s_gb1[c0 + 1], s_gb1[c0 + 2]};
#pragma unroll 4
    for (int a = 0; a < 16; ++a) {
      float Av = s_aeo[jp * 20 + a];
      const float* gr = s_gW1bo + a * 24 + c0;
      g3[0] = fmaf(Av, gr[0], g3[0]);
      g3[1] = fmaf(Av, gr[1], g3[1]);
      g3[2] = fmaf(Av, gr[2], g3[2]);
    }
    s_gb[jp * 28 + c0] = g3[0];
    s_gb[jp * 28 + c0 + 1] = g3[1];
    s_gb[jp * 28 + c0 + 2] = g3[2];
  }
  __syncthreads();

  // ---------------- P2: LN1 closed-form stats + w0*gamma ----------------
  if (tid < 32) {
    float sp = 0.f, qp = 0.f, dwp = 0.f;
#pragma unroll 8
    for (int k = 0; k < 64; ++k) {
      float p = s_pg[tid * 68 + k];
      float w = s_w0[k];
      sp += p;
      qp = fmaf(p, p, qp);
      dwp = fmaf(p, w, dwp);
    }
    ((float4*)s_ex)[tid] = make_float4(sp, qp, dwp, 0.f);
  } else if (tid == 32) {
    float sw = 0.f, qw = 0.f;
    for (int k = 0; k < 64; ++k) {
      float w = s_w0[k];
      sw += w;
      qw = fmaf(w, w, qw);
    }
    s_scal[0] = sw;
    s_scal[1] = qw;
  } else if (tid >= 64 && tid < 128) {
    s_w0g[tid - 64] = s_w0[tid - 64] * s_l1g[tid - 64];
  }
  __syncthreads();

  // ---------------- P3: fold pg *= gamma; W2 B-frags; pair scalars ---------
  {
    int jp = tid >> 3, ks = tid & 7;
    float* pp = s_pg + jp * 68 + ks * 8;
    float4 a0 = *(float4*)pp, a1 = *(float4*)(pp + 4);
    float4 g0 = *(float4*)(s_l1g + ks * 8), g1 = *(float4*)(s_l1g + ks * 8 + 4);
    a0.x *= g0.x; a0.y *= g0.y; a0.z *= g0.z; a0.w *= g0.w;
    a1.x *= g1.x; a1.y *= g1.y; a1.z *= g1.z; a1.w *= g1.w;
    *(float4*)pp = a0;
    *(float4*)(pp + 4) = a1;
  }
  short8 bW2[2][2];
#pragma unroll
  for (int kt = 0; kt < 2; ++kt)
#pragma unroll
    for (int nt = 0; nt < 2; ++nt) {
      U8 t;
#pragma unroll
      for (int p = 0; p < 4; ++p) {
        float lo = ovlf[(kt * 32 + quad * 8 + 2 * p) * 32 + nt * 16 + li];
        float hi = ovlf[(kt * 32 + quad * 8 + 2 * p + 1) * 32 + nt * 16 + li];
        t.u[p] = pkbf(lo, hi);
      }
      bW2[kt][nt] = t.s;
    }
  {
    int j = tid >> 3, b = tid & 7;
    size_t off = (size_t)(btile * 8 + b) * Jv + J0 + j;
    float xv = x[off];
    s_mk[tid] = mask[off];
    float4 ex = ((const float4*)s_ex)[j];
    float mu1 = fmaf(xv, s_scal[0], ex.x) * 0.015625f;
    float Et2 = fmaf(xv * xv, s_scal[1], fmaf(2.0f * xv, ex.z, ex.y)) * 0.015625f;
    float rs1 = rsqrtf(fmaxf(Et2 - mu1 * mu1, 0.f) + 1e-5f);
    *(float4*)(s_pair + tid * 4) = make_float4(xv * rs1, rs1, -mu1 * rs1, 0.f);
  }
  __syncthreads();   // required: s_h (ovl) writes in P4 vs W2 reads in P3

  // ---------------- P4: a-frags -> MFMA h2 -> LN2 -> s_h bf16 ----------
  {
    f32x4 cd[4][2];
    float b2a = s_b2[li], b2b = s_b2[16 + li];
#pragma unroll
    for (int t = 0; t < 4; ++t) {
      cd[t][0][0] = b2a; cd[t][0][1] = b2a; cd[t][0][2] = b2a; cd[t][0][3] = b2a;
      cd[t][1][0] = b2b; cd[t][1][1] = b2b; cd[t][1][2] = b2b; cd[t][1][3] = b2b;
    }
#pragma unroll
    for (int kt = 0; kt < 2; ++kt) {
      int base = kt * 32 + quad * 8;
      float4 wg0 = *(const float4*)(s_w0g + base);
      float4 wg1 = *(const float4*)(s_w0g + base + 4);
      float4 gg0 = *(const float4*)(s_l1g + base);
      float4 gg1 = *(const float4*)(s_l1g + base + 4);
      float4 bb0 = *(const float4*)(s_l1b + base);
      float4 bb1 = *(const float4*)(s_l1b + base + 4);
      float wg[8] = {wg0.x, wg0.y, wg0.z, wg0.w, wg1.x, wg1.y, wg1.z, wg1.w};
      float gg[8] = {gg0.x, gg0.y, gg0.z, gg0.w, gg1.x, gg1.y, gg1.z, gg1.w};
      float bb[8] = {bb0.x, bb0.y, bb0.z, bb0.w, bb1.x, bb1.y, bb1.z, bb1.w};
#pragma unroll
      for (int t = 0; t < 4; ++t) {
        int mrow = wv * 64 + t * 16 + li;
        float4 pr = *(const float4*)(s_pair + mrow * 4);
        const float* pgp = s_pg + (mrow >> 3) * 68 + base;
        float4 p0 = *(const float4*)pgp;
        float4 p1 = *(const float4*)(pgp + 4);
        float pv[8] = {p0.x, p0.y, p0.z, p0.w, p1.x, p1.y, p1.z, p1.w};
        float av[8];
#pragma unroll
        for (int i = 0; i < 8; ++i)
          av[i] = fmaxf(fmaf(pr.x, wg[i], fmaf(pr.y, pv[i], fmaf(pr.z, gg[i], bb[i]))), 0.f);
        U8 a8;
        a8.u[0] = pkbf(av[0], av[1]); a8.u[1] = pkbf(av[2], av[3]);
        a8.u[2] = pkbf(av[4], av[5]); a8.u[3] = pkbf(av[6], av[7]);
        cd[t][0] = __builtin_amdgcn_mfma_f32_16x16x32_bf16(a8.s, bW2[kt][0], cd[t][0], 0, 0, 0);
        cd[t][1] = __builtin_amdgcn_mfma_f32_16x16x32_bf16(a8.s, bW2[kt][1], cd[t][1], 0, 0, 0);
      }
    }
    float g0 = s_l2g[li], be0 = s_l2b[li];
    float g1v = s_l2g[16 + li], be1 = s_l2b[16 + li];
#pragma unroll
    for (int t = 0; t < 4; ++t) {
      float sum[4], sq[4];
#pragma unroll
      for (int r = 0; r < 4; ++r) {
        float a = cd[t][0][r], b = cd[t][1][r];
        sum[r] = a + b;
        sq[r] = fmaf(a, a, b * b);
      }
#pragma unroll
      for (int off = 1; off < 16; off <<= 1) {
#pragma unroll
        for (int r = 0; r < 4; ++r) {
          sum[r] += __shfl_xor(sum[r], off);
          sq[r] += __shfl_xor(sq[r], off);
        }
      }
#pragma unroll
      for (int r = 0; r < 4; ++r) {
        float mu = sum[r] * 0.03125f;
        float var = sq[r] * 0.03125f - mu * mu;
        float rs2 = rsqrtf(fmaxf(var, 0.f) + 1e-5f);
        int m = wv * 64 + t * 16 + quad * 4 + r;
        float h0 = fmaxf(fmaf((cd[t][0][r] - mu) * rs2, g0, be0), 0.f);
        float h1 = fmaxf(fmaf((cd[t][1][r] - mu) * rs2, g1v, be1), 0.f);
        s_h[m * 34 + li] = f2bf(h0);
        s_h[m * 34 + 16 + li] = f2bf(h1);
      }
    }
  }
  // no barrier: P5 touches only own-wave s_h / s_pair rows (in-order DS)

  // ---------------- P5: gate via MFMA + quad-butterfly ----------------
  {
    short8 aG0, aG1;
#pragma unroll
    for (int i = 0; i < 8; ++i) {
      int k = quad * 8 + i;
      aG0[i] = (short)s_gW1bf[k * 24 + li];
      aG1[i] = (li < 8) ? (short)s_gW1bf[k * 24 + 16 + li] : (short)0;
    }
    float4 gw4[2][4];
#pragma unroll
    for (int mt = 0; mt < 2; ++mt)
#pragma unroll
      for (int r = 0; r < 4; ++r) {
        int c = mt * 16 + quad * 4 + r;
        gw4[mt][r] = (c < 24) ? ((const float4*)s_gW2)[c]
                              : make_float4(0.f, 0.f, 0.f, 0.f);
      }
#pragma unroll
    for (int nt = 0; nt < 4; ++nt) {
      int m = wv * 64 + nt * 16 + li;
      U8 bu;
      const unsigned short* hp = s_h + m * 34 + quad * 8;
      bu.u[0] = *(const unsigned int*)(hp + 0);
      bu.u[1] = *(const unsigned int*)(hp + 2);
      bu.u[2] = *(const unsigned int*)(hp + 4);
      bu.u[3] = *(const unsigned int*)(hp + 6);
      int j = m >> 3;
      f32x4 c0, c1;
#pragma unroll
      for (int r = 0; r < 4; ++r) {
        c0[r] = s_gb[j * 28 + quad * 4 + r];
        c1[r] = s_gb[j * 28 + 16 + quad * 4 + r];
      }
      c0 = __builtin_amdgcn_mfma_f32_16x16x32_bf16(aG0, bu.s, c0, 0, 0, 0);
      c1 = __builtin_amdgcn_mfma_f32_16x16x32_bf16(aG1, bu.s, c1, 0, 0, 0);
      float r0 = s_gb2[0], r1 = s_gb2[1], r2 = s_gb2[2], r3 = s_gb2[3];
#pragma unroll
      for (int r = 0; r < 4; ++r) {
        float v0 = fmaxf(c0[r], 0.f);
        float v1 = fmaxf(c1[r], 0.f);
        float4 ga = gw4[0][r], gb = gw4[1][r];
        r0 = fmaf(v0, ga.x, fmaf(v1, gb.x, r0));
        r1 = fmaf(v0, ga.y, fmaf(v1, gb.y, r1));
        r2 = fmaf(v0, ga.z, fmaf(v1, gb.z, r2));
        r3 = fmaf(v0, ga.w, fmaf(v1, gb.w, r3));
      }
      r0 += __shfl_xor(r0, 16); r0 += __shfl_xor(r0, 32);
      r1 += __shfl_xor(r1, 16); r1 += __shfl_xor(r1, 32);
      r2 += __shfl_xor(r2, 16); r2 += __shfl_xor(r2, 32);
      r3 += __shfl_xor(r3, 16); r3 += __shfl_xor(r3, 32);
      r0 = fminf(fmaxf(r0, -10.f), 10.f);
      r1 = fminf(fmaxf(r1, -10.f), 10.f);
      r2 = fminf(fmaxf(r2, -10.f), 10.f);
      r3 = fminf(fmaxf(r3, -10.f), 10.f);
      bool act = (s_mk[m] != 0);
      float e0 = act ? __expf(r0 - 10.f) : 0.f;
      float e1 = act ? __expf(r1 - 10.f) : 0.f;
      float e2 = act ? __expf(r2 - 10.f) : 0.f;
      float e3 = act ? __expf(r3 - 10.f) : 0.f;
      if (quad == 0) *(float4*)(s_pair + m * 4) = make_float4(e0, e1, e2, e3);
    }
  }
  __syncthreads();

  // ---------------- P6: e-h reduce via MFMA (wave handles 2 b's) ----------
  {
    const float* s_e2 = s_pair;
#pragma unroll
    for (int bs = 0; bs < 2; ++bs) {
      int b = wv * 2 + bs;
      float ev[8];
      float separt = 0.f;
#pragma unroll
      for (int i = 0; i < 8; ++i) {
        float v = s_e2[((quad * 8 + i) * 8 + b) * 4 + (li & 3)];
        v = (li < 4) ? v : 0.f;
        ev[i] = v;
        separt += v;
      }
      separt += __shfl_xor(separt, 16);
      separt += __shfl_xor(separt, 32);
      U8 a8;
      a8.u[0] = pkbf(ev[0], ev[1]); a8.u[1] = pkbf(ev[2], ev[3]);
      a8.u[2] = pkbf(ev[4], ev[5]); a8.u[3] = pkbf(ev[6], ev[7]);
#pragma unroll
      for (int half = 0; half < 2; ++half) {
        U8 bh;
#pragma unroll
        for (int p = 0; p < 4; ++p) {
          unsigned int lo = s_h[((quad * 8 + 2 * p) * 8 + b) * 34 + half * 16 + li];
          unsigned int hi = s_h[((quad * 8 + 2 * p + 1) * 8 + b) * 34 + half * 16 + li];
          bh.u[p] = lo | (hi << 16);
        }
        f32x4 c = {0.f, 0.f, 0.f, 0.f};
        c = __builtin_amdgcn_mfma_f32_16x16x32_bf16(a8.s, bh.s, c, 0, 0, 0);
        if (quad == 0) {
          float* dst = acc_g + (size_t)(btile * 8 + b) * 128;
#pragma unroll
          for (int r = 0; r < 4; ++r)
            atomicAdd(dst + r * 32 + half * 16 + li, c[r]);
        }
      }
      if (quad == 0 && li < 4)
        atomicAdd(&se_g[(btile * 8 + b) * 4 + li], separt);
    }
  }

  // ---------------- completion counter + fused tail ----------------
  __threadfence();
  __syncthreads();
  if (tid == 0) s_last = (atomicAdd(cnt, 1) == NBLK - 1) ? 1 : 0;
  __syncthreads();
  if (!s_last) return;
  __threadfence();

  float* tw = ((float*)s_ovl) + wv * 288;
  float* t_hs = tw;
  float* t_comb = tw + 128;
  float* t_e1 = tw + 160;
  for (int it = 0; it < 16; ++it) {
    int b = wv * 16 + it;
    float sev = 0.f;
    if (lane < 4) sev = atomicAdd(&se_g[b * 4 + lane], 0.f);
    float se0 = __shfl(sev, 0);
    bool empty = !(se0 > 0.f);
    float a0 = atomicAdd(&acc_g[(size_t)b * 128 + lane], 0.f);
    float a1 = atomicAdd(&acc_g[(size_t)b * 128 + 64 + lane], 0.f);
    float sw0 = __shfl(sev, lane >> 5);
    float sw1 = __shfl(sev, 2 + (lane >> 5));
    t_hs[lane] = empty ? 0.f : a0 * (1.f / sw0);
    t_hs[64 + lane] = empty ? 0.f : a1 * (1.f / sw1);
    if (lane < 32) {
      float cp = cb[lane];
#pragma unroll 8
      for (int i = 0; i < 128; ++i) cp = fmaf(t_hs[i], cW[i * 32 + lane], cp);
      float ssum = cp;
#pragma unroll
      for (int off = 16; off > 0; off >>= 1) ssum += __shfl_xor(ssum, off, 32);
      float mu = ssum * (1.f / 32.f);
      float dd = cp - mu;
      float sq = dd * dd;
#pragma unroll
      for (int off = 16; off > 0; off >>= 1) sq += __shfl_xor(sq, off, 32);
      float rs = rsqrtf(sq * (1.f / 32.f) + 1e-5f);
      float comb = fmaxf(fmaf(dd * rs, clng[lane], clnb[lane]), 0.f);
      if (empty) comb = 0.f;
      t_comb[lane] = comb;
    }
    float v0 = eb1[lane], v1 = eb1[64 + lane];
#pragma unroll
    for (int i = 0; i < 32; ++i) {
      float c = t_comb[i];
      v0 = fmaf(c, eW1[i * 128 + lane], v0);
      v1 = fmaf(c, eW1[i * 128 + 64 + lane], v1);
    }
    float ssum = v0 + v1;
#pragma unroll
    for (int off = 32; off > 0; off >>= 1) ssum += __shfl_xor(ssum, off, 64);
    float mu = ssum * (1.f / 128.f);
    float d0 = v0 - mu, d1 = v1 - mu;
    float sq = fmaf(d0, d0, d1 * d1);
#pragma unroll
    for (int off = 32; off > 0; off >>= 1) sq += __shfl_xor(sq, off, 64);
    float rs = rsqrtf(sq * (1.f / 128.f) + 1e-5f);
    t_e1[lane] = fmaxf(d0 * rs, 0.f);
    t_e1[64 + lane] = fmaxf(d1 * rs, 0.f);
    float v = eb2[lane];
#pragma unroll 8
    for (int i = 0; i < 128; ++i) v = fmaf(t_e1[i], eW2[i * 64 + lane], v);
    ssum = v;
#pragma unroll
    for (int off = 32; off > 0; off >>= 1) ssum += __shfl_xor(ssum, off, 64);
    mu = ssum * (1.f / 64.f);
    float dv = v - mu;
    sq = dv * dv;
#pragma unroll
    for (int off = 32; off > 0; off >>= 1) sq += __shfl_xor(sq, off, 64);
    rs = rsqrtf(sq * (1.f / 64.f) + 1e-5f);
    float o = fmaxf(dv * rs, 0.f);
    if (lane < 32)
      out[b * 32 + lane] = o;                    // mu
    else
      out[Bv * 32 + b * 32 + (lane - 32)] = o;   // logvar
  }
}

extern "C" void kernel_launch(void* const* d_in, const int* in_sizes, int n_in,
                              void* d_out, int out_size, void* d_ws, size_t ws_size,
                              hipStream_t stream) {
  const float* x    = (const float*)d_in[0];
  const int* mask   = (const int*)d_in[1];
  const int* atse   = (const int*)d_in[2];
  const float* fe   = (const float*)d_in[3];
  const float* ae   = (const float*)d_in[4];
  const float* hW1  = (const float*)d_in[5];
  const float* hb1  = (const float*)d_in[6];
  const float* hl1g = (const float*)d_in[7];
  const float* hl1b = (const float*)d_in[8];
  const float* hW2  = (const float*)d_in[9];
  const float* hb2  = (const float*)d_in[10];
  const float* hl2g = (const float*)d_in[11];
  const float* hl2b = (const float*)d_in[12];
  const float* gW1  = (const float*)d_in[13];
  const float* gb1  = (const float*)d_in[14];
  const float* gW2  = (const float*)d_in[15];
  const float* gb2  = (const float*)d_in[16];
  const float* cW   = (const float*)d_in[17];
  const float* cb   = (const float*)d_in[18];
  const float* clng = (const float*)d_in[19];
  const float* clnb = (const float*)d_in[20];
  const float* eW1  = (const float*)d_in[21];
  const float* eb1  = (const float*)d_in[22];
  const float* eW2  = (const float*)d_in[23];
  const float* eb2  = (const float*)d_in[24];
  float* out = (float*)d_out;

  float* ws = (float*)d_ws;
  float* accg = ws;                        // B*128 floats
  float* seg  = accg + Bv * 128;           // B*4 floats
  int* cnt    = (int*)(seg + Bv * 4);      // completion counter

  hipMemsetAsync(accg, 0, (Bv * 128 + Bv * 4) * sizeof(float) + sizeof(int), stream);

  pe_fused<<<dim3(NBT, NJT), dim3(256), 0, stream>>>(
      x, mask, atse, fe, ae, hW1, hb1, hl1g, hl1b, hW2, hb2, hl2g, hl2b,
      gW1, gb1, gW2, gb2, cW, cb, clng, clnb, eW1, eb1, eW2, eb2,
      accg, seg, cnt, out);
}

// Round 10
// 231.126 us; speedup vs baseline: 2.5398x; 2.5398x over previous
//
#include <hip/hip_runtime.h>
#include <hip/hip_bf16.h>
#include <math.h>

#define Bv 64
#define Jv 20000
#define NJT 625   // j tiles (32 j each)
#define NBT 8     // b tiles (8 b each)

typedef __attribute__((ext_vector_type(8))) short short8;
typedef __attribute__((ext_vector_type(4))) float f32x4;

union U8 { short8 s; unsigned int u[4]; };

__device__ __forceinline__ unsigned short f2bf(float f) {
  unsigned int u = __float_as_uint(f);
  u += 0x7FFFu + ((u >> 16) & 1u);
  return (unsigned short)(u >> 16);
}
__device__ __forceinline__ unsigned int pkbf(float a, float b) {
  __hip_bfloat162 h = __float22bfloat162_rn(make_float2(a, b));
  union { __hip_bfloat162 h; unsigned int u; } c;
  c.h = h;
  return c.u;  // a in low 16, b in high 16
}
__device__ __forceinline__ float bflo(unsigned int u) { return __uint_as_float(u << 16); }
__device__ __forceinline__ float bfhi(unsigned int u) { return __uint_as_float(u & 0xFFFF0000u); }

// Block = 32 j x 8 b = 256 pairs (m = j*8 + b), 256 threads.
// pre1 / h@W2 / gate-L1 / e-h reduce via MFMA. Tail is a SEPARATE dispatch
// (R9 lesson: one-block serial tail = 350us of unhidden global latency).
__global__ __launch_bounds__(256) void pe_fused(
    const float* __restrict__ x, const int* __restrict__ mask,
    const int* __restrict__ atse_idx, const float* __restrict__ fe,
    const float* __restrict__ ae,
    const float* __restrict__ hW1, const float* __restrict__ hb1,
    const float* __restrict__ hl1g, const float* __restrict__ hl1b,
    const float* __restrict__ hW2, const float* __restrict__ hb2,
    const float* __restrict__ hl2g, const float* __restrict__ hl2b,
    const float* __restrict__ gW1, const float* __restrict__ gb1,
    const float* __restrict__ gW2, const float* __restrict__ gb2,
    float* __restrict__ acc_g, float* __restrict__ se_g) {
  __shared__ __align__(16) float s_pg[32 * 68];      // pre1, then pre1*gamma
  __shared__ __align__(16) float s_ex[32 * 4];       // sp, qp, dwp per j
  __shared__ __align__(16) float s_gb[32 * 28 + 16]; // gate bias per j (+pad)
  __shared__ __align__(16) float s_pair[256 * 4];    // P3-P4: pair scalars; P5-P6: e
  __shared__ __align__(16) float s_w0[64], s_w0g[64], s_l1g[64], s_l1b[64];
  __shared__ __align__(16) float s_b2[32], s_l2g[32], s_l2b[32];
  __shared__ __align__(16) float s_gb1[24], s_gW2[96];
  __shared__ float s_gb2[4], s_scal[2];
  __shared__ int s_mk[256];
  __shared__ __align__(16) unsigned short s_gW1bf[32 * 24];
  // overlay: P0-P3 (float): [0..2048) W2 | [2048..2688) ae | [2688..3072) gW1b
  //          P4-P6: s_h bf16 [256][34]
  __shared__ __align__(16) unsigned short s_ovl[256 * 34];

  int tid = threadIdx.x;
  int btile = blockIdx.x;   // 0..7
  int jtile = blockIdx.y;   // 0..624
  int J0 = jtile * 32;
  int lane = tid & 63, wv = tid >> 6;
  int li = lane & 15, quad = lane >> 4;

  float* ovlf = (float*)s_ovl;
  float* s_aeo = ovlf + 2048;
  float* s_gW1bo = ovlf + 2688;
  unsigned short* s_h = s_ovl;  // ho bf16, stride 34 (P4+)

  // ---------------- P0: stage globals ----------------
  for (int i = tid; i < 2048; i += 256) ovlf[i] = hW2[i];
  for (int i = tid; i < 768; i += 256) s_gW1bf[i] = f2bf(gW1[i]);
  for (int i = tid; i < 384; i += 256) s_gW1bo[i] = gW1[768 + i];
  if (tid < 96) s_gW2[tid] = gW2[tid];
  if (tid < 64) { s_w0[tid] = hW1[tid]; s_l1g[tid] = hl1g[tid]; s_l1b[tid] = hl1b[tid]; }
  if (tid < 32) { s_b2[tid] = hb2[tid]; s_l2g[tid] = hl2g[tid]; s_l2b[tid] = hl2b[tid]; }
  if (tid < 24) s_gb1[tid] = gb1[tid];
  if (tid < 4) s_gb2[tid] = gb2[tid];
  if (tid < 128) s_gb[(tid >> 2) * 28 + 24 + (tid & 3)] = 0.f;  // cols 24..27
  if (tid >= 128 && tid < 144) s_gb[32 * 28 + (tid - 128)] = 0.f;
  if (tid < 32) {
    int ai = atse_idx[J0 + tid];
    const float4* av = (const float4*)(ae + (size_t)ai * 16);
#pragma unroll
    for (int q = 0; q < 4; ++q) *(float4*)(s_aeo + tid * 20 + q * 4) = av[q];
  }
  __syncthreads();

  // ---------------- P1: pre1 via MFMA ----------------
  {
    U8 bH;
#pragma unroll
    for (int p = 0; p < 4; ++p) {
      float lo = hW1[(1 + quad * 8 + 2 * p) * 64 + wv * 16 + li];
      float hi = hW1[(1 + quad * 8 + 2 * p + 1) * 64 + wv * 16 + li];
      bH.u[p] = pkbf(lo, hi);
    }
    float hb = hb1[wv * 16 + li];
    f32x4 cP;
#pragma unroll
    for (int mt = 0; mt < 2; ++mt) {
      cP[0] = hb; cP[1] = hb; cP[2] = hb; cP[3] = hb;
      const float* fp = fe + (size_t)(J0 + mt * 16 + li) * 32 + quad * 8;
      float4 f0 = *(const float4*)fp;
      float4 f1 = *(const float4*)(fp + 4);
      U8 aF;
      aF.u[0] = pkbf(f0.x, f0.y); aF.u[1] = pkbf(f0.z, f0.w);
      aF.u[2] = pkbf(f1.x, f1.y); aF.u[3] = pkbf(f1.z, f1.w);
      cP = __builtin_amdgcn_mfma_f32_16x16x32_bf16(aF.s, bH.s, cP, 0, 0, 0);
#pragma unroll
      for (int r = 0; r < 4; ++r)
        s_pg[(mt * 16 + quad * 4 + r) * 68 + wv * 16 + li] = cP[r];
    }
  }
  // gate bias per j (8 threads per j, 3 c's per thread)
  {
    int jp = tid >> 3, ks = tid & 7;
    int c0 = ks * 3;
    float g3[3] = {s_gb1[c0], s_gb1[c0 + 1], s_gb1[c0 + 2]};
#pragma unroll 4
    for (int a = 0; a < 16; ++a) {
      float Av = s_aeo[jp * 20 + a];
      const float* gr = s_gW1bo + a * 24 + c0;
      g3[0] = fmaf(Av, gr[0], g3[0]);
      g3[1] = fmaf(Av, gr[1], g3[1]);
      g3[2] = fmaf(Av, gr[2], g3[2]);
    }
    s_gb[jp * 28 + c0] = g3[0];
    s_gb[jp * 28 + c0 + 1] = g3[1];
    s_gb[jp * 28 + c0 + 2] = g3[2];
  }
  __syncthreads();

  // ---------------- P2: LN1 closed-form stats + w0*gamma ----------------
  if (tid < 32) {
    float sp = 0.f, qp = 0.f, dwp = 0.f;
#pragma unroll 8
    for (int k = 0; k < 64; ++k) {
      float p = s_pg[tid * 68 + k];
      float w = s_w0[k];
      sp += p;
      qp = fmaf(p, p, qp);
      dwp = fmaf(p, w, dwp);
    }
    ((float4*)s_ex)[tid] = make_float4(sp, qp, dwp, 0.f);
  } else if (tid == 32) {
    float sw = 0.f, qw = 0.f;
    for (int k = 0; k < 64; ++k) {
      float w = s_w0[k];
      sw += w;
      qw = fmaf(w, w, qw);
    }
    s_scal[0] = sw;
    s_scal[1] = qw;
  } else if (tid >= 64 && tid < 128) {
    s_w0g[tid - 64] = s_w0[tid - 64] * s_l1g[tid - 64];
  }
  __syncthreads();

  // ---------------- P3: fold pg *= gamma; W2 B-frags; pair scalars ---------
  {
    int jp = tid >> 3, ks = tid & 7;
    float* pp = s_pg + jp * 68 + ks * 8;
    float4 a0 = *(float4*)pp, a1 = *(float4*)(pp + 4);
    float4 g0 = *(float4*)(s_l1g + ks * 8), g1 = *(float4*)(s_l1g + ks * 8 + 4);
    a0.x *= g0.x; a0.y *= g0.y; a0.z *= g0.z; a0.w *= g0.w;
    a1.x *= g1.x; a1.y *= g1.y; a1.z *= g1.z; a1.w *= g1.w;
    *(float4*)pp = a0;
    *(float4*)(pp + 4) = a1;
  }
  short8 bW2[2][2];
#pragma unroll
  for (int kt = 0; kt < 2; ++kt)
#pragma unroll
    for (int nt = 0; nt < 2; ++nt) {
      U8 t;
#pragma unroll
      for (int p = 0; p < 4; ++p) {
        float lo = ovlf[(kt * 32 + quad * 8 + 2 * p) * 32 + nt * 16 + li];
        float hi = ovlf[(kt * 32 + quad * 8 + 2 * p + 1) * 32 + nt * 16 + li];
        t.u[p] = pkbf(lo, hi);
      }
      bW2[kt][nt] = t.s;
    }
  {
    int j = tid >> 3, b = tid & 7;
    size_t off = (size_t)(btile * 8 + b) * Jv + J0 + j;
    float xv = x[off];
    s_mk[tid] = mask[off];
    float4 ex = ((const float4*)s_ex)[j];
    float mu1 = fmaf(xv, s_scal[0], ex.x) * 0.015625f;
    float Et2 = fmaf(xv * xv, s_scal[1], fmaf(2.0f * xv, ex.z, ex.y)) * 0.015625f;
    float rs1 = rsqrtf(fmaxf(Et2 - mu1 * mu1, 0.f) + 1e-5f);
    *(float4*)(s_pair + tid * 4) = make_float4(xv * rs1, rs1, -mu1 * rs1, 0.f);
  }
  __syncthreads();   // required: s_h (ovl) writes in P4 vs W2 reads in P3

  // ---------------- P4: a-frags -> MFMA h2 -> LN2 -> s_h bf16 ----------
  {
    f32x4 cd[4][2];
    float b2a = s_b2[li], b2b = s_b2[16 + li];
#pragma unroll
    for (int t = 0; t < 4; ++t) {
      cd[t][0][0] = b2a; cd[t][0][1] = b2a; cd[t][0][2] = b2a; cd[t][0][3] = b2a;
      cd[t][1][0] = b2b; cd[t][1][1] = b2b; cd[t][1][2] = b2b; cd[t][1][3] = b2b;
    }
#pragma unroll
    for (int kt = 0; kt < 2; ++kt) {
      int base = kt * 32 + quad * 8;
      float4 wg0 = *(const float4*)(s_w0g + base);
      float4 wg1 = *(const float4*)(s_w0g + base + 4);
      float4 gg0 = *(const float4*)(s_l1g + base);
      float4 gg1 = *(const float4*)(s_l1g + base + 4);
      float4 bb0 = *(const float4*)(s_l1b + base);
      float4 bb1 = *(const float4*)(s_l1b + base + 4);
      float wg[8] = {wg0.x, wg0.y, wg0.z, wg0.w, wg1.x, wg1.y, wg1.z, wg1.w};
      float gg[8] = {gg0.x, gg0.y, gg0.z, gg0.w, gg1.x, gg1.y, gg1.z, gg1.w};
      float bb[8] = {bb0.x, bb0.y, bb0.z, bb0.w, bb1.x, bb1.y, bb1.z, bb1.w};
#pragma unroll
      for (int t = 0; t < 4; ++t) {
        int mrow = wv * 64 + t * 16 + li;
        float4 pr = *(const float4*)(s_pair + mrow * 4);
        const float* pgp = s_pg + (mrow >> 3) * 68 + base;
        float4 p0 = *(const float4*)pgp;
        float4 p1 = *(const float4*)(pgp + 4);
        float pv[8] = {p0.x, p0.y, p0.z, p0.w, p1.x, p1.y, p1.z, p1.w};
        float av[8];
#pragma unroll
        for (int i = 0; i < 8; ++i)
          av[i] = fmaxf(fmaf(pr.x, wg[i], fmaf(pr.y, pv[i], fmaf(pr.z, gg[i], bb[i]))), 0.f);
        U8 a8;
        a8.u[0] = pkbf(av[0], av[1]); a8.u[1] = pkbf(av[2], av[3]);
        a8.u[2] = pkbf(av[4], av[5]); a8.u[3] = pkbf(av[6], av[7]);
        cd[t][0] = __builtin_amdgcn_mfma_f32_16x16x32_bf16(a8.s, bW2[kt][0], cd[t][0], 0, 0, 0);
        cd[t][1] = __builtin_amdgcn_mfma_f32_16x16x32_bf16(a8.s, bW2[kt][1], cd[t][1], 0, 0, 0);
      }
    }
    float g0 = s_l2g[li], be0 = s_l2b[li];
    float g1v = s_l2g[16 + li], be1 = s_l2b[16 + li];
#pragma unroll
    for (int t = 0; t < 4; ++t) {
      float sum[4], sq[4];
#pragma unroll
      for (int r = 0; r < 4; ++r) {
        float a = cd[t][0][r], b = cd[t][1][r];
        sum[r] = a + b;
        sq[r] = fmaf(a, a, b * b);
      }
#pragma unroll
      for (int off = 1; off < 16; off <<= 1) {
#pragma unroll
        for (int r = 0; r < 4; ++r) {
          sum[r] += __shfl_xor(sum[r], off);
          sq[r] += __shfl_xor(sq[r], off);
        }
      }
#pragma unroll
      for (int r = 0; r < 4; ++r) {
        float mu = sum[r] * 0.03125f;
        float var = sq[r] * 0.03125f - mu * mu;
        float rs2 = rsqrtf(fmaxf(var, 0.f) + 1e-5f);
        int m = wv * 64 + t * 16 + quad * 4 + r;
        float h0 = fmaxf(fmaf((cd[t][0][r] - mu) * rs2, g0, be0), 0.f);
        float h1 = fmaxf(fmaf((cd[t][1][r] - mu) * rs2, g1v, be1), 0.f);
        s_h[m * 34 + li] = f2bf(h0);
        s_h[m * 34 + 16 + li] = f2bf(h1);
      }
    }
  }
  // no barrier: P5 touches only own-wave s_h / s_pair rows (in-order DS)

  // ---------------- P5: gate via MFMA + quad-butterfly ----------------
  {
    short8 aG0, aG1;
#pragma unroll
    for (int i = 0; i < 8; ++i) {
      int k = quad * 8 + i;
      aG0[i] = (short)s_gW1bf[k * 24 + li];
      aG1[i] = (li < 8) ? (short)s_gW1bf[k * 24 + 16 + li] : (short)0;
    }
    float4 gw4[2][4];
#pragma unroll
    for (int mt = 0; mt < 2; ++mt)
#pragma unroll
      for (int r = 0; r < 4; ++r) {
        int c = mt * 16 + quad * 4 + r;
        gw4[mt][r] = (c < 24) ? ((const float4*)s_gW2)[c]
                              : make_float4(0.f, 0.f, 0.f, 0.f);
      }
#pragma unroll
    for (int nt = 0; nt < 4; ++nt) {
      int m = wv * 64 + nt * 16 + li;
      U8 bu;
      const unsigned short* hp = s_h + m * 34 + quad * 8;
      bu.u[0] = *(const unsigned int*)(hp + 0);
      bu.u[1] = *(const unsigned int*)(hp + 2);
      bu.u[2] = *(const unsigned int*)(hp + 4);
      bu.u[3] = *(const unsigned int*)(hp + 6);
      int j = m >> 3;
      f32x4 c0, c1;
#pragma unroll
      for (int r = 0; r < 4; ++r) {
        c0[r] = s_gb[j * 28 + quad * 4 + r];
        c1[r] = s_gb[j * 28 + 16 + quad * 4 + r];
      }
      c0 = __builtin_amdgcn_mfma_f32_16x16x32_bf16(aG0, bu.s, c0, 0, 0, 0);
      c1 = __builtin_amdgcn_mfma_f32_16x16x32_bf16(aG1, bu.s, c1, 0, 0, 0);
      float r0 = s_gb2[0], r1 = s_gb2[1], r2 = s_gb2[2], r3 = s_gb2[3];
#pragma unroll
      for (int r = 0; r < 4; ++r) {
        float v0 = fmaxf(c0[r], 0.f);
        float v1 = fmaxf(c1[r], 0.f);
        float4 ga = gw4[0][r], gb = gw4[1][r];
        r0 = fmaf(v0, ga.x, fmaf(v1, gb.x, r0));
        r1 = fmaf(v0, ga.y, fmaf(v1, gb.y, r1));
        r2 = fmaf(v0, ga.z, fmaf(v1, gb.z, r2));
        r3 = fmaf(v0, ga.w, fmaf(v1, gb.w, r3));
      }
      r0 += __shfl_xor(r0, 16); r0 += __shfl_xor(r0, 32);
      r1 += __shfl_xor(r1, 16); r1 += __shfl_xor(r1, 32);
      r2 += __shfl_xor(r2, 16); r2 += __shfl_xor(r2, 32);
      r3 += __shfl_xor(r3, 16); r3 += __shfl_xor(r3, 32);
      r0 = fminf(fmaxf(r0, -10.f), 10.f);
      r1 = fminf(fmaxf(r1, -10.f), 10.f);
      r2 = fminf(fmaxf(r2, -10.f), 10.f);
      r3 = fminf(fmaxf(r3, -10.f), 10.f);
      bool act = (s_mk[m] != 0);
      float e0 = act ? __expf(r0 - 10.f) : 0.f;
      float e1 = act ? __expf(r1 - 10.f) : 0.f;
      float e2 = act ? __expf(r2 - 10.f) : 0.f;
      float e3 = act ? __expf(r3 - 10.f) : 0.f;
      if (quad == 0) *(float4*)(s_pair + m * 4) = make_float4(e0, e1, e2, e3);
    }
  }
  __syncthreads();

  // ---------------- P6: e-h reduce via MFMA (wave handles 2 b's) ----------
  {
    const float* s_e2 = s_pair;
#pragma unroll
    for (int bs = 0; bs < 2; ++bs) {
      int b = wv * 2 + bs;
      float ev[8];
      float separt = 0.f;
#pragma unroll
      for (int i = 0; i < 8; ++i) {
        float v = s_e2[((quad * 8 + i) * 8 + b) * 4 + (li & 3)];
        v = (li < 4) ? v : 0.f;
        ev[i] = v;
        separt += v;
      }
      separt += __shfl_xor(separt, 16);
      separt += __shfl_xor(separt, 32);
      U8 a8;
      a8.u[0] = pkbf(ev[0], ev[1]); a8.u[1] = pkbf(ev[2], ev[3]);
      a8.u[2] = pkbf(ev[4], ev[5]); a8.u[3] = pkbf(ev[6], ev[7]);
#pragma unroll
      for (int half = 0; half < 2; ++half) {
        U8 bh;
#pragma unroll
        for (int p = 0; p < 4; ++p) {
          unsigned int lo = s_h[((quad * 8 + 2 * p) * 8 + b) * 34 + half * 16 + li];
          unsigned int hi = s_h[((quad * 8 + 2 * p + 1) * 8 + b) * 34 + half * 16 + li];
          bh.u[p] = lo | (hi << 16);
        }
        f32x4 c = {0.f, 0.f, 0.f, 0.f};
        c = __builtin_amdgcn_mfma_f32_16x16x32_bf16(a8.s, bh.s, c, 0, 0, 0);
        if (quad == 0) {
          float* dst = acc_g + (size_t)(btile * 8 + b) * 128;
#pragma unroll
          for (int r = 0; r < 4; ++r)
            atomicAdd(dst + r * 32 + half * 16 + li, c[r]);
        }
      }
      if (quad == 0 && li < 4)
        atomicAdd(&se_g[(btile * 8 + b) * 4 + li], separt);
    }
  }
}

// ---------------- per-b tail: normalize, c-layer, encoder MLP ----------------
__global__ __launch_bounds__(64) void pe_tail(
    const float* __restrict__ acc_g, const float* __restrict__ se_g,
    const float* __restrict__ cW, const float* __restrict__ cb,
    const float* __restrict__ clng, const float* __restrict__ clnb,
    const float* __restrict__ eW1, const float* __restrict__ eb1,
    const float* __restrict__ eW2, const float* __restrict__ eb2,
    float* __restrict__ out) {
  int b = blockIdx.x;
  int lane = threadIdx.x;  // 64 threads = 1 wave
  __shared__ float s_hs[128], s_comb[32], s_e1[128];

  float se0 = se_g[b * 4 + 0];
  bool empty = !(se0 > 0.0f);
  float inv[4];
#pragma unroll
  for (int w = 0; w < 4; ++w) {
    float sw = se_g[b * 4 + w];
    inv[w] = empty ? 0.0f : 1.0f / sw;
  }
  s_hs[lane] = acc_g[b * 128 + lane] * inv[lane >> 5];
  s_hs[lane + 64] = acc_g[b * 128 + lane + 64] * inv[(lane + 64) >> 5];
  __syncthreads();

  if (lane < 32) {
    float cp = cb[lane];
#pragma unroll 8
    for (int i = 0; i < 128; ++i) cp = fmaf(s_hs[i], cW[i * 32 + lane], cp);
    float ssum = cp;
#pragma unroll
    for (int off = 16; off > 0; off >>= 1) ssum += __shfl_xor(ssum, off, 32);
    float mu = ssum * (1.0f / 32.0f);
    float dd = cp - mu;
    float sq = dd * dd;
#pragma unroll
    for (int off = 16; off > 0; off >>= 1) sq += __shfl_xor(sq, off, 32);
    float rs = rsqrtf(sq * (1.0f / 32.0f) + 1e-5f);
    float comb = fmaxf(fmaf(dd * rs, clng[lane], clnb[lane]), 0.0f);
    if (empty) comb = 0.0f;
    s_comb[lane] = comb;
  }
  __syncthreads();

  float v0 = eb1[lane], v1 = eb1[lane + 64];
#pragma unroll
  for (int i = 0; i < 32; ++i) {
    float c = s_comb[i];
    v0 = fmaf(c, eW1[i * 128 + lane], v0);
    v1 = fmaf(c, eW1[i * 128 + lane + 64], v1);
  }
  float ssum = v0 + v1;
#pragma unroll
  for (int off = 32; off > 0; off >>= 1) ssum += __shfl_xor(ssum, off, 64);
  float mu = ssum * (1.0f / 128.0f);
  float d0 = v0 - mu, d1 = v1 - mu;
  float sq = fmaf(d0, d0, d1 * d1);
#pragma unroll
  for (int off = 32; off > 0; off >>= 1) sq += __shfl_xor(sq, off, 64);
  float rs = rsqrtf(sq * (1.0f / 128.0f) + 1e-5f);
  s_e1[lane] = fmaxf(d0 * rs, 0.0f);
  s_e1[lane + 64] = fmaxf(d1 * rs, 0.0f);
  __syncthreads();

  float v = eb2[lane];
#pragma unroll 8
  for (int i = 0; i < 128; ++i) v = fmaf(s_e1[i], eW2[i * 64 + lane], v);
  ssum = v;
#pragma unroll
  for (int off = 32; off > 0; off >>= 1) ssum += __shfl_xor(ssum, off, 64);
  mu = ssum * (1.0f / 64.0f);
  float dv = v - mu;
  sq = dv * dv;
#pragma unroll
  for (int off = 32; off > 0; off >>= 1) sq += __shfl_xor(sq, off, 64);
  rs = rsqrtf(sq * (1.0f / 64.0f) + 1e-5f);
  float o = fmaxf(dv * rs, 0.0f);
  if (lane < 32)
    out[b * 32 + lane] = o;                       // mu
  else
    out[Bv * 32 + b * 32 + (lane - 32)] = o;      // logvar
}

extern "C" void kernel_launch(void* const* d_in, const int* in_sizes, int n_in,
                              void* d_out, int out_size, void* d_ws, size_t ws_size,
                              hipStream_t stream) {
  const float* x    = (const float*)d_in[0];
  const int* mask   = (const int*)d_in[1];
  const int* atse   = (const int*)d_in[2];
  const float* fe   = (const float*)d_in[3];
  const float* ae   = (const float*)d_in[4];
  const float* hW1  = (const float*)d_in[5];
  const float* hb1  = (const float*)d_in[6];
  const float* hl1g = (const float*)d_in[7];
  const float* hl1b = (const float*)d_in[8];
  const float* hW2  = (const float*)d_in[9];
  const float* hb2  = (const float*)d_in[10];
  const float* hl2g = (const float*)d_in[11];
  const float* hl2b = (const float*)d_in[12];
  const float* gW1  = (const float*)d_in[13];
  const float* gb1  = (const float*)d_in[14];
  const float* gW2  = (const float*)d_in[15];
  const float* gb2  = (const float*)d_in[16];
  const float* cW   = (const float*)d_in[17];
  const float* cb   = (const float*)d_in[18];
  const float* clng = (const float*)d_in[19];
  const float* clnb = (const float*)d_in[20];
  const float* eW1  = (const float*)d_in[21];
  const float* eb1  = (const float*)d_in[22];
  const float* eW2  = (const float*)d_in[23];
  const float* eb2  = (const float*)d_in[24];
  float* out = (float*)d_out;

  float* ws = (float*)d_ws;
  float* accg = ws;                 // B*128 floats
  float* seg  = accg + Bv * 128;    // B*4 floats

  hipMemsetAsync(accg, 0, (Bv * 128 + Bv * 4) * sizeof(float), stream);

  pe_fused<<<dim3(NBT, NJT), dim3(256), 0, stream>>>(
      x, mask, atse, fe, ae, hW1, hb1, hl1g, hl1b, hW2, hb2, hl2g, hl2b,
      gW1, gb1, gW2, gb2, accg, seg);
  pe_tail<<<dim3(Bv), dim3(64), 0, stream>>>(
      accg, seg, cW, cb, clng, clnb, eW1, eb1, eW2, eb2, out);
}